// Round 1
// baseline (395.389 us; speedup 1.0000x reference)
//
#include <hip/hip_runtime.h>

// Problem constants (fixed by reference)
#define B_ 16
#define C_ 64
#define T_ 2048
#define O_ 64
#define KNN 3
#define JSPLIT 8
#define JCHUNK (T_ / JSPLIT)   // 256
#define BS_STR 68              // LDS row stride (floats); %4==0 keeps b128 alignment

// Workspace layout (float offsets). Total = 3,682,304 floats = 14.73 MB.
#define XT_OFF 0                                  // xT[b][t][c]  : B*T*C
#define WL_OFF (B_ * T_ * C_)                     // Wl[o][k*64+c]: O*192
#define PD_OFF (WL_OFF + O_ * 192)                // partial dists: B*T*JSPLIT*3
#define PI_OFF (PD_OFF + B_ * T_ * JSPLIT * 3)    // partial idx  : B*T*JSPLIT*3

// ---------------------------------------------------------------------------
// Prep: transpose x (B,C,T) -> xT (B,T,C) and W (O,C,K) -> Wl[o][k*64+c]
// ---------------------------------------------------------------------------
__global__ __launch_bounds__(256) void prep_kernel(const float* __restrict__ x,
                                                   const float* __restrict__ W,
                                                   float* __restrict__ ws) {
    float* xT = ws + XT_OFF;
    float* Wl = ws + WL_OFF;
    int blk = blockIdx.x;
    int tid = threadIdx.x;
    if (blk < B_ * (T_ / 64)) {
        int b  = blk / (T_ / 64);
        int t0 = (blk % (T_ / 64)) * 64;
        __shared__ float tl[64 * 65];
        #pragma unroll
        for (int r = 0; r < 16; ++r) {
            int e = r * 256 + tid;
            int c = e >> 6, t = e & 63;
            tl[c * 65 + t] = x[(b * C_ + c) * T_ + t0 + t];  // coalesced in t
        }
        __syncthreads();
        #pragma unroll
        for (int r = 0; r < 16; ++r) {
            int e = r * 256 + tid;
            int t = e >> 6, c = e & 63;
            xT[(b * T_ + t0 + t) * 64 + c] = tl[c * 65 + t];  // coalesced in c
        }
    } else {
        // W transpose: e enumerates (o*64+c)*3+k (read-coalesced)
        int e = (blk - B_ * (T_ / 64)) * 256 + tid;
        if (e < O_ * C_ * KNN) {
            int o = e / (C_ * KNN);
            int c = (e / KNN) % C_;
            int k = e % KNN;
            Wl[o * 192 + k * 64 + c] = W[e];
        }
    }
}

// ---------------------------------------------------------------------------
// Main: all-pairs dist (rank-equivalent score s_j = nsq_j - 2*dot) + top-3.
// Single-wave blocks; lane owns 2 query rows (A in 128 VGPRs); j split 8-way.
// ---------------------------------------------------------------------------
__global__ __launch_bounds__(64) void knn_topk_kernel(const float* __restrict__ xT,
                                                      float* __restrict__ pd,
                                                      int* __restrict__ pi) {
    __shared__ float Bs[64 * BS_STR];
    __shared__ float nsqS[64];

    int blk   = blockIdx.x;        // 0..2047
    int ib    = blk / JSPLIT;      // i-block id 0..255
    int q     = blk % JSPLIT;      // j chunk
    int b     = ib / (T_ / 128);
    int iBase = (ib % (T_ / 128)) * 128;
    int l     = threadIdx.x;       // lane 0..63
    const float* xTb = xT + b * T_ * 64;

    // A fragments: lane owns rows iBase+l and iBase+64+l (64 ch each)
    float4 a0[16], a1[16];
    {
        const float4* rA = (const float4*)(xTb + (iBase + l) * 64);
        const float4* rB = (const float4*)(xTb + (iBase + 64 + l) * 64);
        #pragma unroll
        for (int c4 = 0; c4 < 16; ++c4) { a0[c4] = rA[c4]; a1[c4] = rB[c4]; }
    }

    const float INF = __builtin_inff();
    float d0a = INF, d1a = INF, d2a = INF, d0b = INF, d1b = INF, d2b = INF;
    int   j0a = 0, j1a = 0, j2a = 0, j0b = 0, j1b = 0, j2b = 0;

    int jstart = q * JCHUNK;
    for (int jt = jstart; jt < jstart + JCHUNK; jt += 64) {
        __syncthreads();
        {   // stage B tile: lane l loads row jt+l (256B) -> Bs[l][:], plus nsq
            const float4* rowJ = (const float4*)(xTb + (jt + l) * 64);
            float4* dst = (float4*)(Bs + l * BS_STR);
            float nx = 0.f, ny = 0.f, nz = 0.f, nw = 0.f;
            #pragma unroll 4
            for (int c4 = 0; c4 < 16; ++c4) {
                float4 v = rowJ[c4];
                nx = fmaf(v.x, v.x, nx); ny = fmaf(v.y, v.y, ny);
                nz = fmaf(v.z, v.z, nz); nw = fmaf(v.w, v.w, nw);
                dst[c4] = v;
            }
            nsqS[l] = (nx + ny) + (nz + nw);
        }
        __syncthreads();

        #pragma unroll 1
        for (int jj = 0; jj < 64; ++jj) {
            const float4* br = (const float4*)(Bs + jj * BS_STR);
            float snj = nsqS[jj];
            float px = 0.f, py = 0.f, pz = 0.f, pw = 0.f;
            float qx = 0.f, qy = 0.f, qz = 0.f, qw = 0.f;
            #pragma unroll
            for (int c4 = 0; c4 < 16; ++c4) {
                float4 w = br[c4];   // broadcast ds_read_b128
                px = fmaf(w.x, a0[c4].x, px); py = fmaf(w.y, a0[c4].y, py);
                pz = fmaf(w.z, a0[c4].z, pz); pw = fmaf(w.w, a0[c4].w, pw);
                qx = fmaf(w.x, a1[c4].x, qx); qy = fmaf(w.y, a1[c4].y, qy);
                qz = fmaf(w.z, a1[c4].z, qz); qw = fmaf(w.w, a1[c4].w, qw);
            }
            float s0 = snj - 2.f * ((px + py) + (pz + pw));
            float s1 = snj - 2.f * ((qx + qy) + (qz + qw));
            int jg = jt + jj;
            {   // branchless sorted top-3 insert, strict < => lower-index tie-break
                bool b2 = s0 < d2a, b1 = s0 < d1a, b0 = s0 < d0a;
                float nd2 = b1 ? d1a : (b2 ? s0 : d2a); int ni2 = b1 ? j1a : (b2 ? jg : j2a);
                float nd1 = b0 ? d0a : (b1 ? s0 : d1a); int ni1 = b0 ? j0a : (b1 ? jg : j1a);
                float nd0 = b0 ? s0 : d0a;              int ni0 = b0 ? jg : j0a;
                d2a = nd2; j2a = ni2; d1a = nd1; j1a = ni1; d0a = nd0; j0a = ni0;
            }
            {
                bool b2 = s1 < d2b, b1 = s1 < d1b, b0 = s1 < d0b;
                float nd2 = b1 ? d1b : (b2 ? s1 : d2b); int ni2 = b1 ? j1b : (b2 ? jg : j2b);
                float nd1 = b0 ? d0b : (b1 ? s1 : d1b); int ni1 = b0 ? j0b : (b1 ? jg : j1b);
                float nd0 = b0 ? s1 : d0b;              int ni0 = b0 ? jg : j0b;
                d2b = nd2; j2b = ni2; d1b = nd1; j1b = ni1; d0b = nd0; j0b = ni0;
            }
        }
    }

    int ra = b * T_ + iBase + l;
    int rb = ra + 64;
    int basea = (ra * JSPLIT + q) * 3;
    int baseb = (rb * JSPLIT + q) * 3;
    pd[basea] = d0a; pd[basea + 1] = d1a; pd[basea + 2] = d2a;
    pi[basea] = j0a; pi[basea + 1] = j1a; pi[basea + 2] = j2a;
    pd[baseb] = d0b; pd[baseb + 1] = d1b; pd[baseb + 2] = d2b;
    pi[baseb] = j0b; pi[baseb + 1] = j1b; pi[baseb + 2] = j2b;
}

// ---------------------------------------------------------------------------
// Merge partials + gather + conv. One block (64 thr) per (b, i); thread = o.
// ---------------------------------------------------------------------------
__global__ __launch_bounds__(64) void conv_kernel(const float* __restrict__ ws,
                                                  const float* __restrict__ bias,
                                                  float* __restrict__ out) {
    const float* xT = ws + XT_OFF;
    const float* Wl = ws + WL_OFF;
    const float* pd = ws + PD_OFF;
    const int*   pi = (const int*)(ws + PI_OFF);

    int blk = blockIdx.x;
    int b = blk / T_;
    int i = blk % T_;
    int tid = threadIdx.x;

    __shared__ int   jsel[KNN];
    __shared__ float g[192];

    if (tid == 0) {
        const float INF = __builtin_inff();
        float D0 = INF, D1 = INF, D2 = INF; int I0 = 0, I1 = 0, I2 = 0;
        int base = (b * T_ + i) * (JSPLIT * 3);
        // chunks scanned in ascending-j order; strict < keeps lower index on ties
        for (int qq = 0; qq < JSPLIT * 3; ++qq) {
            float d = pd[base + qq]; int id = pi[base + qq];
            if (d < D2) {
                if (d < D1) {
                    D2 = D1; I2 = I1;
                    if (d < D0) { D1 = D0; I1 = I0; D0 = d; I0 = id; }
                    else        { D1 = d; I1 = id; }
                } else { D2 = d; I2 = id; }
            }
        }
        jsel[0] = I0; jsel[1] = I1; jsel[2] = I2;
    }
    __syncthreads();
    if (tid < 48) {   // gather 3 neighbor rows (k-major): g[k*64+c]
        int k = tid >> 4, c4 = tid & 15;
        float4 v = *(const float4*)(xT + (b * T_ + jsel[k]) * 64 + c4 * 4);
        *(float4*)(g + k * 64 + c4 * 4) = v;
    }
    __syncthreads();

    int o = tid;
    float ax = 0.f, ay = 0.f, az = 0.f, aw = 0.f;
    const float4* wrow = (const float4*)(Wl + o * 192);
    #pragma unroll
    for (int m4 = 0; m4 < 48; ++m4) {
        float4 wv = wrow[m4];                       // per-lane, L1/L2-resident
        float4 gv = *(const float4*)(g + m4 * 4);   // LDS broadcast
        ax = fmaf(wv.x, gv.x, ax); ay = fmaf(wv.y, gv.y, ay);
        az = fmaf(wv.z, gv.z, az); aw = fmaf(wv.w, gv.w, aw);
    }
    float acc = bias[o] + ((ax + ay) + (az + aw));
    out[(b * O_ + o) * T_ + i] = acc;
}

// ---------------------------------------------------------------------------
extern "C" void kernel_launch(void* const* d_in, const int* in_sizes, int n_in,
                              void* d_out, int out_size, void* d_ws, size_t ws_size,
                              hipStream_t stream) {
    const float* x    = (const float*)d_in[0];
    const float* W    = (const float*)d_in[1];
    const float* bias = (const float*)d_in[2];
    float* out = (float*)d_out;
    float* ws  = (float*)d_ws;
    // needs ~14.8 MB workspace (xT 8MB + Wl 48KB + partials 6.3MB)

    prep_kernel<<<B_ * (T_ / 64) + 48, 256, 0, stream>>>(x, W, ws);
    knn_topk_kernel<<<(B_ * T_ / 128) * JSPLIT, 64, 0, stream>>>(
        ws + XT_OFF, ws + PD_OFF, (int*)(ws + PI_OFF));
    conv_kernel<<<B_ * T_, 64, 0, stream>>>(ws, bias, out);
}

// Round 2
// 274.520 us; speedup vs baseline: 1.4403x; 1.4403x over previous
//
#include <hip/hip_runtime.h>

// Problem constants (fixed by reference)
#define B_ 16
#define C_ 64
#define T_ 2048
#define O_ 64
#define KNN 3
#define JSPLIT 8
#define JCHUNK (T_ / JSPLIT)   // 256
#define BS_STR 68              // LDS row stride (floats); %4==0 keeps b128 alignment

// Workspace layout (float offsets). Total = 3,682,304 floats = 14.73 MB (proven to fit).
#define XT_OFF 0                                  // xT[b][t][c]  : B*T*C
#define WT_OFF (B_ * T_ * C_)                     // Wt[m][o] m=k*64+c : 192*64
#define PD_OFF (WT_OFF + 192 * O_)                // partial dists: B*T*JSPLIT*3
#define PI_OFF (PD_OFF + B_ * T_ * JSPLIT * 3)    // partial idx  : B*T*JSPLIT*3

// ---------------------------------------------------------------------------
// Prep: transpose x (B,C,T) -> xT (B,T,C) and W (O,C,K) -> Wt[k*64+c][o]
// ---------------------------------------------------------------------------
__global__ __launch_bounds__(256) void prep_kernel(const float* __restrict__ x,
                                                   const float* __restrict__ W,
                                                   float* __restrict__ ws) {
    float* xT = ws + XT_OFF;
    float* Wt = ws + WT_OFF;
    int blk = blockIdx.x;
    int tid = threadIdx.x;
    if (blk < B_ * (T_ / 64)) {
        int b  = blk / (T_ / 64);
        int t0 = (blk % (T_ / 64)) * 64;
        __shared__ float tl[64 * 65];
        #pragma unroll
        for (int r = 0; r < 16; ++r) {
            int e = r * 256 + tid;
            int c = e >> 6, t = e & 63;
            tl[c * 65 + t] = x[(b * C_ + c) * T_ + t0 + t];  // coalesced in t
        }
        __syncthreads();
        #pragma unroll
        for (int r = 0; r < 16; ++r) {
            int e = r * 256 + tid;
            int t = e >> 6, c = e & 63;
            xT[(b * T_ + t0 + t) * 64 + c] = tl[c * 65 + t];  // coalesced in c
        }
    } else {
        // W transpose: e enumerates (o*64+c)*3+k (read-coalesced)
        int e = (blk - B_ * (T_ / 64)) * 256 + tid;
        if (e < O_ * C_ * KNN) {
            int o = e / (C_ * KNN);
            int c = (e / KNN) % C_;
            int k = e % KNN;
            Wt[(k * 64 + c) * O_ + o] = W[e];
        }
    }
}

// ---------------------------------------------------------------------------
// Main: all-pairs dist (rank-equivalent score s_j = nsq_j - 2*dot) + top-3.
// Single-wave blocks; lane owns 2 query rows (A in 128 VGPRs); j split 8-way.
// ---------------------------------------------------------------------------
__global__ __launch_bounds__(64) void knn_topk_kernel(const float* __restrict__ xT,
                                                      float* __restrict__ pd,
                                                      int* __restrict__ pi) {
    __shared__ float Bs[64 * BS_STR];
    __shared__ float nsqS[64];

    int blk   = blockIdx.x;        // 0..2047
    int ib    = blk / JSPLIT;      // i-block id 0..255
    int q     = blk % JSPLIT;      // j chunk
    int b     = ib / (T_ / 128);
    int iBase = (ib % (T_ / 128)) * 128;
    int l     = threadIdx.x;       // lane 0..63
    const float* xTb = xT + b * T_ * 64;

    // A fragments: lane owns rows iBase+l and iBase+64+l (64 ch each)
    float4 a0[16], a1[16];
    {
        const float4* rA = (const float4*)(xTb + (iBase + l) * 64);
        const float4* rB = (const float4*)(xTb + (iBase + 64 + l) * 64);
        #pragma unroll
        for (int c4 = 0; c4 < 16; ++c4) { a0[c4] = rA[c4]; a1[c4] = rB[c4]; }
    }

    const float INF = __builtin_inff();
    float d0a = INF, d1a = INF, d2a = INF, d0b = INF, d1b = INF, d2b = INF;
    int   j0a = 0, j1a = 0, j2a = 0, j0b = 0, j1b = 0, j2b = 0;

    int jstart = q * JCHUNK;
    for (int jt = jstart; jt < jstart + JCHUNK; jt += 64) {
        __syncthreads();
        {   // stage B tile: lane l loads row jt+l (256B) -> Bs[l][:], plus nsq
            const float4* rowJ = (const float4*)(xTb + (jt + l) * 64);
            float4* dst = (float4*)(Bs + l * BS_STR);
            float nx = 0.f, ny = 0.f, nz = 0.f, nw = 0.f;
            #pragma unroll 4
            for (int c4 = 0; c4 < 16; ++c4) {
                float4 v = rowJ[c4];
                nx = fmaf(v.x, v.x, nx); ny = fmaf(v.y, v.y, ny);
                nz = fmaf(v.z, v.z, nz); nw = fmaf(v.w, v.w, nw);
                dst[c4] = v;
            }
            nsqS[l] = (nx + ny) + (nz + nw);
        }
        __syncthreads();

        #pragma unroll 2
        for (int jj = 0; jj < 64; ++jj) {
            const float4* br = (const float4*)(Bs + jj * BS_STR);
            float snj = nsqS[jj];
            float px = 0.f, py = 0.f, pz = 0.f, pw = 0.f;
            float qx = 0.f, qy = 0.f, qz = 0.f, qw = 0.f;
            #pragma unroll
            for (int c4 = 0; c4 < 16; ++c4) {
                float4 w = br[c4];   // broadcast ds_read_b128
                px = fmaf(w.x, a0[c4].x, px); py = fmaf(w.y, a0[c4].y, py);
                pz = fmaf(w.z, a0[c4].z, pz); pw = fmaf(w.w, a0[c4].w, pw);
                qx = fmaf(w.x, a1[c4].x, qx); qy = fmaf(w.y, a1[c4].y, qy);
                qz = fmaf(w.z, a1[c4].z, qz); qw = fmaf(w.w, a1[c4].w, qw);
            }
            float s0 = snj - 2.f * ((px + py) + (pz + pw));
            float s1 = snj - 2.f * ((qx + qy) + (qz + qw));
            int jg = jt + jj;
            {   // branchless sorted top-3 insert, strict < => lower-index tie-break
                bool b2 = s0 < d2a, b1 = s0 < d1a, b0 = s0 < d0a;
                float nd2 = b1 ? d1a : (b2 ? s0 : d2a); int ni2 = b1 ? j1a : (b2 ? jg : j2a);
                float nd1 = b0 ? d0a : (b1 ? s0 : d1a); int ni1 = b0 ? j0a : (b1 ? jg : j1a);
                float nd0 = b0 ? s0 : d0a;              int ni0 = b0 ? jg : j0a;
                d2a = nd2; j2a = ni2; d1a = nd1; j1a = ni1; d0a = nd0; j0a = ni0;
            }
            {
                bool b2 = s1 < d2b, b1 = s1 < d1b, b0 = s1 < d0b;
                float nd2 = b1 ? d1b : (b2 ? s1 : d2b); int ni2 = b1 ? j1b : (b2 ? jg : j2b);
                float nd1 = b0 ? d0b : (b1 ? s1 : d1b); int ni1 = b0 ? j0b : (b1 ? jg : j1b);
                float nd0 = b0 ? s1 : d0b;              int ni0 = b0 ? jg : j0b;
                d2b = nd2; j2b = ni2; d1b = nd1; j1b = ni1; d0b = nd0; j0b = ni0;
            }
        }
    }

    int ra = b * T_ + iBase + l;
    int rb = ra + 64;
    int basea = (ra * JSPLIT + q) * 3;
    int baseb = (rb * JSPLIT + q) * 3;
    pd[basea] = d0a; pd[basea + 1] = d1a; pd[basea + 2] = d2a;
    pi[basea] = j0a; pi[basea + 1] = j1a; pi[basea + 2] = j2a;
    pd[baseb] = d0b; pd[baseb + 1] = d1b; pd[baseb + 2] = d2b;
    pi[baseb] = j0b; pi[baseb + 1] = j1b; pi[baseb + 2] = j2b;
}

// ---------------------------------------------------------------------------
// Merge: 1 thread per (b,i). Merges its own 24 partials (ascending-j chunk
// order, strict < => reference tie-break) and writes jsel in-place into the
// first 3 slots of its OWN pi region (thread-private -> no race).
// ---------------------------------------------------------------------------
__global__ __launch_bounds__(256) void merge_kernel(float* __restrict__ ws) {
    const float* pd = ws + PD_OFF;
    int*         pi = (int*)(ws + PI_OFF);
    int t = blockIdx.x * 256 + threadIdx.x;   // 0 .. B*T-1
    int base = t * (JSPLIT * 3);
    const float INF = __builtin_inff();
    float D0 = INF, D1 = INF, D2 = INF; int I0 = 0, I1 = 0, I2 = 0;
    #pragma unroll
    for (int qq = 0; qq < JSPLIT * 3; ++qq) {
        float d = pd[base + qq]; int id = pi[base + qq];
        if (d < D2) {
            if (d < D1) {
                D2 = D1; I2 = I1;
                if (d < D0) { D1 = D0; I1 = I0; D0 = d; I0 = id; }
                else        { D1 = d; I1 = id; }
            } else { D2 = d; I2 = id; }
        }
    }
    pi[base] = I0; pi[base + 1] = I1; pi[base + 2] = I2;
}

// ---------------------------------------------------------------------------
// Conv: block = (b, 64-wide i-tile), 256 threads. Stage Wt (48KB) + gathered
// neighbor tile g[m][i'] (48KB) in LDS; 16x16 thread grid computes 4o x 4i
// register tiles; float4 stores contiguous in i (coalesced, no write amp).
// ---------------------------------------------------------------------------
__global__ __launch_bounds__(256) void conv2_kernel(const float* __restrict__ ws,
                                                    const float* __restrict__ bias,
                                                    float* __restrict__ out) {
    const float* xT = ws + XT_OFF;
    const int*   pi = (const int*)(ws + PI_OFF);

    __shared__ float Wt_s[192 * 64];
    __shared__ float g_s[192 * 64];

    int b  = blockIdx.x >> 5;            // 32 i-tiles of 64
    int i0 = (blockIdx.x & 31) * 64;
    int tid = threadIdx.x;

    // stage Wt (coalesced float4 copy)
    {
        const float4* WtG = (const float4*)(ws + WT_OFF);
        float4* WtS = (float4*)Wt_s;
        #pragma unroll
        for (int r = 0; r < 12; ++r) WtS[r * 256 + tid] = WtG[r * 256 + tid];
    }
    // gather: 192 units (k, i'), each loads one neighbor row (256B contiguous)
    if (tid < 192) {
        int k  = tid >> 6;               // 0..2
        int ip = tid & 63;               // i' within tile
        int j  = pi[(b * T_ + i0 + ip) * (JSPLIT * 3) + k];
        const float4* src = (const float4*)(xT + (b * T_ + j) * 64);
        #pragma unroll
        for (int c4 = 0; c4 < 16; ++c4) {
            float4 v = src[c4];
            int m = k * 64 + c4 * 4;
            g_s[(m + 0) * 64 + ip] = v.x;
            g_s[(m + 1) * 64 + ip] = v.y;
            g_s[(m + 2) * 64 + ip] = v.z;
            g_s[(m + 3) * 64 + ip] = v.w;
        }
    }
    __syncthreads();

    int oq = tid >> 4;                   // 0..15 -> o = oq*4..oq*4+3
    int iq = tid & 15;                   // 0..15 -> i' = iq*4..iq*4+3
    float acc[4][4] = {{0.f}};
    #pragma unroll 4
    for (int m = 0; m < 192; ++m) {
        float4 wv = *(const float4*)(Wt_s + m * 64 + oq * 4);  // broadcast x16
        float4 gv = *(const float4*)(g_s  + m * 64 + iq * 4);  // broadcast x4
        acc[0][0] = fmaf(wv.x, gv.x, acc[0][0]); acc[0][1] = fmaf(wv.x, gv.y, acc[0][1]);
        acc[0][2] = fmaf(wv.x, gv.z, acc[0][2]); acc[0][3] = fmaf(wv.x, gv.w, acc[0][3]);
        acc[1][0] = fmaf(wv.y, gv.x, acc[1][0]); acc[1][1] = fmaf(wv.y, gv.y, acc[1][1]);
        acc[1][2] = fmaf(wv.y, gv.z, acc[1][2]); acc[1][3] = fmaf(wv.y, gv.w, acc[1][3]);
        acc[2][0] = fmaf(wv.z, gv.x, acc[2][0]); acc[2][1] = fmaf(wv.z, gv.y, acc[2][1]);
        acc[2][2] = fmaf(wv.z, gv.z, acc[2][2]); acc[2][3] = fmaf(wv.z, gv.w, acc[2][3]);
        acc[3][0] = fmaf(wv.w, gv.x, acc[3][0]); acc[3][1] = fmaf(wv.w, gv.y, acc[3][1]);
        acc[3][2] = fmaf(wv.w, gv.z, acc[3][2]); acc[3][3] = fmaf(wv.w, gv.w, acc[3][3]);
    }
    #pragma unroll
    for (int po = 0; po < 4; ++po) {
        int o = oq * 4 + po;
        float bv = bias[o];
        float4 r;
        r.x = acc[po][0] + bv; r.y = acc[po][1] + bv;
        r.z = acc[po][2] + bv; r.w = acc[po][3] + bv;
        // contiguous in i across iq -> coalesced 256B segments per o-row
        *(float4*)(out + (b * O_ + o) * T_ + i0 + iq * 4) = r;
    }
}

// ---------------------------------------------------------------------------
extern "C" void kernel_launch(void* const* d_in, const int* in_sizes, int n_in,
                              void* d_out, int out_size, void* d_ws, size_t ws_size,
                              hipStream_t stream) {
    const float* x    = (const float*)d_in[0];
    const float* W    = (const float*)d_in[1];
    const float* bias = (const float*)d_in[2];
    float* out = (float*)d_out;
    float* ws  = (float*)d_ws;

    prep_kernel<<<B_ * (T_ / 64) + 48, 256, 0, stream>>>(x, W, ws);
    knn_topk_kernel<<<(B_ * T_ / 128) * JSPLIT, 64, 0, stream>>>(
        ws + XT_OFF, ws + PD_OFF, (int*)(ws + PI_OFF));
    merge_kernel<<<B_ * T_ / 256, 256, 0, stream>>>(ws);
    conv2_kernel<<<B_ * 32, 256, 0, stream>>>(ws, bias, out);
}